// Round 7
// baseline (251.903 us; speedup 1.0000x reference)
//
#include <hip/hip_runtime.h>
#include <hip/hip_bf16.h>

#define IN_F 8192
#define OUT_F 8192
#define SEQ 64
#define LORA_R 16

typedef __attribute__((ext_vector_type(4))) float f32x4;
typedef __attribute__((ext_vector_type(4))) int i32x4;
typedef _Float16 f16x2 __attribute__((ext_vector_type(2)));
typedef _Float16 f16x8 __attribute__((ext_vector_type(8)));

typedef __attribute__((address_space(3))) unsigned int lds_u32;
typedef const __attribute__((address_space(1))) unsigned int glb_u32;

__device__ __forceinline__ void gl_lds16(const void* g, void* l) {
    __builtin_amdgcn_global_load_lds((glb_u32*)g, (lds_u32*)l, 16, 0, 0);
}

__device__ __forceinline__ f16x8 cvt8(const f32x4 a, const f32x4 b) {
    f16x8 r;
    r[0] = (_Float16)a.x; r[1] = (_Float16)a.y; r[2] = (_Float16)a.z; r[3] = (_Float16)a.w;
    r[4] = (_Float16)b.x; r[5] = (_Float16)b.y; r[6] = (_Float16)b.z; r[7] = (_Float16)b.w;
    return r;
}

#define VMCNT(n) asm volatile("s_waitcnt vmcnt(" #n ")" ::: "memory")

// ---- single fused kernel: 256 blocks (one 32-col n-tile, FULL K), 512 thr = 8 waves ----
// W: global_load_lds (pre-XOR'd global src, linear LDS dest), 3-deep.
// x: reg-staged f32->f16 (issue at kt for kt+2, cvt+ds_write at kt for kt+1), swizzled write.
// LoRA t = x@A^T computed IN-LOOP on nh==0 waves: 4 extra MFMA reusing af[] as A-operand,
// per-lane A-row fragment (r = c16) as B-operand; reduced across wkk waves in epilogue.
// Mixed-stream FIFO vmcnt: steady 7 (nh0) / 5 (nh1); tails 6/2/0 and 4/0.
// LDS (115200 B): xs 4x[64*128]f16 | wt 4x[32*64]int | scs [32*132]f32
// epilogue alias: accs[8][64*17] over xs; tred[4][64][16] over scs; tfin[64][16] over wt.
__global__ __launch_bounds__(512, 2) void k_fused(
    const float* __restrict__ x, const int* __restrict__ packed,
    const float* __restrict__ scales, const float* __restrict__ A,
    const float* __restrict__ B, float* __restrict__ out) {
    __shared__ char lds[115200];
    _Float16* xs = (_Float16*)lds;            // 4 x 16384 B
    int* wt = (int*)(lds + 65536);            // 4 x 8192 B
    float* scs = (float*)(lds + 98304);       // 16896 B
    float* accs = (float*)lds;                // epilogue alias (34816 B)
    float* tred = scs;                        // epilogue alias (16384 B)
    float* tfin = (float*)(lds + 65536);      // epilogue alias (4096 B)

    const int tid = threadIdx.x;
    const int n0 = blockIdx.x * 32;
    const int w = tid >> 6, lane = tid & 63;
    const int nh = w >> 2, wkk = w & 3;
    const int q = lane >> 4, c16 = lane & 15;
    const int lrow = lane >> 4, lcol = lane & 15;

    // ---- scales staging (drained before pipeline issues start) ----
    {
        int row = tid >> 4, g = tid & 15;
        const float* sp = scales + (n0 + row) * (IN_F / 64);
        *(f32x4*)(scs + row * 132 + g * 4)      = *(const f32x4*)(sp + g * 4);
        *(f32x4*)(scs + row * 132 + 64 + g * 4) = *(const f32x4*)(sp + 64 + g * 4);
    }
    __builtin_amdgcn_sched_barrier(0);

    // ---- addresses ----
    const int wr = w * 4 + lrow;
    const int* wgp = packed + (long)(n0 + wr) * (IN_F / 2) + ((lcol ^ (wr & 7)) << 2);
    int* wd = wt + w * 256;                    // + buf*2048

    const int xr0 = w * 8 + lrow, xr1 = xr0 + 4;
    const float* xg0 = x + (size_t)xr0 * IN_F + lcol * 8;
    const float* xg1 = x + (size_t)xr1 * IN_F + lcol * 8;
    const int xw0 = xr0 * 128 + ((lcol ^ (xr0 & 7)) << 3);   // f16 index, swizzled
    const int xw1 = xr1 * 128 + ((lcol ^ (xr1 & 7)) << 3);

    const float* ag = A + (size_t)c16 * IN_F + wkk * 32 + q * 8;   // LoRA A row = c16

    // loop-invariant swizzled read offsets (unchanged from verified kernel)
    const int pvo = (nh * 16 + c16) * 64 + ((wkk * 16 + q * 4) ^ ((c16 & 7) << 2));
    int afo[4];
    #pragma unroll
    for (int mt = 0; mt < 4; ++mt)
        afo[mt] = (mt * 16 + c16) * 128 + ((wkk * 32 + q * 8) ^ ((c16 & 7) << 3));
    const int sco = (nh * 16 + c16) * 132 + (wkk >> 1);

    f32x4 acc[4], tac[4];
    #pragma unroll
    for (int mt = 0; mt < 4; ++mt) {
        acc[mt] = (f32x4){0.f, 0.f, 0.f, 0.f};
        tac[mt] = (f32x4){0.f, 0.f, 0.f, 0.f};
    }

    f32x4 gxA[4], gxB[4], aA[2], aB[2];

    // ---- prologue: W chunks 0-2 (gl_lds), x chunks 0-1 (regs), A chunk 0 ----
    gl_lds16(wgp,       wd);
    gl_lds16(wgp +  64, wd + 2048);
    gl_lds16(wgp + 128, wd + 4096);
    gxA[0] = *(const f32x4*)(xg0);       gxA[1] = *(const f32x4*)(xg0 + 4);
    gxA[2] = *(const f32x4*)(xg1);       gxA[3] = *(const f32x4*)(xg1 + 4);
    gxB[0] = *(const f32x4*)(xg0 + 128); gxB[1] = *(const f32x4*)(xg0 + 132);
    gxB[2] = *(const f32x4*)(xg1 + 128); gxB[3] = *(const f32x4*)(xg1 + 132);
    if (nh == 0) { aB[0] = *(const f32x4*)(ag); aB[1] = *(const f32x4*)(ag + 4); }
    // x chunk 0 -> buf 0 (compiler inserts the vm wait for gxA; leaves gxB/aB in flight)
    *(f16x8*)(xs + xw0) = cvt8(gxA[0], gxA[1]);
    *(f16x8*)(xs + xw1) = cvt8(gxA[2], gxA[3]);
    asm volatile("s_waitcnt lgkmcnt(0)" ::: "memory");

    const f16x2 c1032 = {(_Float16)1032.0f, (_Float16)1032.0f};

    auto body = [&](int kt, f32x4 (&gxI)[4], f32x4 (&gxC)[4],
                    f32x4 (&aI)[2], f32x4 (&aC)[2]) __attribute__((always_inline)) {
        __builtin_amdgcn_s_barrier();
        __builtin_amdgcn_sched_barrier(0);
        const int cur = kt & 3;
        // issues (this iter's 7 / 5): W(kt+3), x(kt+2), A(kt+1)
        if (kt <= 60) gl_lds16(wgp + (kt + 3) * 64, wd + ((kt + 3) & 3) * 2048);
        if (kt <= 61) {
            const float* p0 = xg0 + (size_t)(kt + 2) * 128;
            const float* p1 = xg1 + (size_t)(kt + 2) * 128;
            gxI[0] = *(const f32x4*)(p0); gxI[1] = *(const f32x4*)(p0 + 4);
            gxI[2] = *(const f32x4*)(p1); gxI[3] = *(const f32x4*)(p1 + 4);
        }
        if (nh == 0 && kt <= 62) {
            const float* pa = ag + (size_t)(kt + 1) * 128;
            aI[0] = *(const f32x4*)(pa); aI[1] = *(const f32x4*)(pa + 4);
        }
        // main compute from buf cur
        i32x4 pv = *(const i32x4*)(wt + cur * 2048 + pvo);
        float scf = scs[sco + kt * 2];
        _Float16 sch = (_Float16)scf;
        f16x2 sc2 = {sch, sch};
        f16x8 bf;
        #pragma unroll
        for (int m = 0; m < 4; ++m) {
            unsigned u = ((((unsigned)pv[m] << 12) | (unsigned)pv[m]) & 0x000F000Fu) | 0x64006400u;
            f16x2 h = __builtin_bit_cast(f16x2, u);
            h = (h - c1032) * sc2;          // exact (q-8)*scale
            bf[2 * m] = h.x;
            bf[2 * m + 1] = h.y;
        }
        const _Float16* xbase = xs + cur * 8192;
        f16x8 af0 = *(const f16x8*)(xbase + afo[0]);
        f16x8 af1 = *(const f16x8*)(xbase + afo[1]);
        f16x8 af2 = *(const f16x8*)(xbase + afo[2]);
        f16x8 af3 = *(const f16x8*)(xbase + afo[3]);
        acc[0] = __builtin_amdgcn_mfma_f32_16x16x32_f16(af0, bf, acc[0], 0, 0, 0);
        acc[1] = __builtin_amdgcn_mfma_f32_16x16x32_f16(af1, bf, acc[1], 0, 0, 0);
        acc[2] = __builtin_amdgcn_mfma_f32_16x16x32_f16(af2, bf, acc[2], 0, 0, 0);
        acc[3] = __builtin_amdgcn_mfma_f32_16x16x32_f16(af3, bf, acc[3], 0, 0, 0);
        // mid-iter FIFO wait: completes everything issued BEFORE this iteration
        if (nh == 0) {
            if (kt <= 60)      VMCNT(7);
            else if (kt == 61) VMCNT(6);
            else if (kt == 62) VMCNT(2);
            else               VMCNT(0);
        } else {
            if (kt <= 60)      VMCNT(5);
            else if (kt == 61) VMCNT(4);
            else               VMCNT(0);
        }
        __builtin_amdgcn_sched_barrier(0);
        // LoRA t MFMAs (A chunk kt, loaded last iter)
        if (nh == 0) {
            f16x8 afr = cvt8(aC[0], aC[1]);
            tac[0] = __builtin_amdgcn_mfma_f32_16x16x32_f16(af0, afr, tac[0], 0, 0, 0);
            tac[1] = __builtin_amdgcn_mfma_f32_16x16x32_f16(af1, afr, tac[1], 0, 0, 0);
            tac[2] = __builtin_amdgcn_mfma_f32_16x16x32_f16(af2, afr, tac[2], 0, 0, 0);
            tac[3] = __builtin_amdgcn_mfma_f32_16x16x32_f16(af3, afr, tac[3], 0, 0, 0);
        }
        // x chunk kt+1 (loaded last iter) -> LDS buf (kt+1)&3
        if (kt <= 62) {
            const int nb = (kt + 1) & 3;
            *(f16x8*)(xs + nb * 8192 + xw0) = cvt8(gxC[0], gxC[1]);
            *(f16x8*)(xs + nb * 8192 + xw1) = cvt8(gxC[2], gxC[3]);
        }
        asm volatile("s_waitcnt lgkmcnt(0)" ::: "memory");
    };

    for (int kt = 0; kt < 64; kt += 2) {
        body(kt,     gxA, gxB, aA, aB);
        body(kt + 1, gxB, gxA, aB, aA);
    }
    __syncthreads();   // all waves done with xs/wt/scs before alias overwrite

    // ---- epilogue ----
    // GEMM partials -> accs (alias xs)
    float* myacc = accs + w * (64 * 17);
    #pragma unroll
    for (int mt = 0; mt < 4; ++mt)
        #pragma unroll
        for (int r = 0; r < 4; ++r)
            myacc[(mt * 16 + q * 4 + r) * 17 + c16] = acc[mt][r];
    // t partials (nh0 waves w=0..3) -> tred (alias scs): [w][s][16]
    if (nh == 0) {
        #pragma unroll
        for (int mt = 0; mt < 4; ++mt)
            #pragma unroll
            for (int r = 0; r < 4; ++r)
                tred[w * 1024 + (mt * 16 + q * 4 + r) * 16 + c16] = tac[mt][r];
    }
    __syncthreads();
    // reduce t across the 4 wkk waves -> tfin (alias wt): [s][16]
    {
        int p = tid;   // entries p and p+512 of 1024
        tfin[p]       = tred[p]       + tred[1024 + p]       + tred[2048 + p]       + tred[3072 + p];
        tfin[p + 512] = tred[p + 512] + tred[1024 + p + 512] + tred[2048 + p + 512] + tred[3072 + p + 512];
    }
    __syncthreads();

    #pragma unroll
    for (int j = 0; j < 4; ++j) {
        int p = tid + j * 512;                    // 2048 outputs: s in 0..63, c in 0..31
        int s = p >> 5, c = p & 31;
        const float* ab = accs + (c >> 4) * 4 * (64 * 17) + s * 17 + (c & 15);
        float v = ab[0] + ab[64 * 17] + ab[2 * 64 * 17] + ab[3 * 64 * 17];
        const float* trow = tfin + s * 16;
        const float* bp = B + (n0 + c) * LORA_R;
        f32x4 t0 = *(const f32x4*)trow,        t1 = *(const f32x4*)(trow + 4);
        f32x4 t2 = *(const f32x4*)(trow + 8),  t3 = *(const f32x4*)(trow + 12);
        f32x4 b0 = *(const f32x4*)bp,       b1 = *(const f32x4*)(bp + 4);
        f32x4 b2 = *(const f32x4*)(bp + 8), b3 = *(const f32x4*)(bp + 12);
        float lr = t0.x * b0.x + t0.y * b0.y + t0.z * b0.z + t0.w * b0.w
                 + t1.x * b1.x + t1.y * b1.y + t1.z * b1.z + t1.w * b1.w
                 + t2.x * b2.x + t2.y * b2.y + t2.z * b2.z + t2.w * b2.w
                 + t3.x * b3.x + t3.y * b3.y + t3.z * b3.z + t3.w * b3.w;
        v += 2.0f * lr;
        out[s * OUT_F + n0 + c] = v;
    }
}

extern "C" void kernel_launch(void* const* d_in, const int* in_sizes, int n_in,
                              void* d_out, int out_size, void* d_ws, size_t ws_size,
                              hipStream_t stream) {
    const float* x      = (const float*)d_in[0];
    const int* packed   = (const int*)d_in[1];
    const float* scales = (const float*)d_in[2];
    const float* lora_A = (const float*)d_in[3];
    const float* lora_B = (const float*)d_in[4];
    float* out = (float*)d_out;

    k_fused<<<256, 512, 0, stream>>>(x, packed, scales, lora_A, lora_B, out);
}

// Round 8
// 210.271 us; speedup vs baseline: 1.1980x; 1.1980x over previous
//
#include <hip/hip_runtime.h>
#include <hip/hip_bf16.h>

#define IN_F 8192
#define OUT_F 8192
#define SEQ 64
#define LORA_R 16

typedef __attribute__((ext_vector_type(4))) float f32x4;
typedef __attribute__((ext_vector_type(4))) int i32x4;
typedef __attribute__((ext_vector_type(4))) unsigned short u16x4;
typedef _Float16 f16x2 __attribute__((ext_vector_type(2)));
typedef _Float16 f16x8 __attribute__((ext_vector_type(8)));

typedef __attribute__((address_space(3))) unsigned int lds_u32;
typedef const __attribute__((address_space(1))) unsigned int glb_u32;

__device__ __forceinline__ void gl_lds16(const void* g, void* l) {
    __builtin_amdgcn_global_load_lds((glb_u32*)g, (lds_u32*)l, 16, 0, 0);
}

#define VMCNT(n) asm volatile("s_waitcnt vmcnt(" #n ")" ::: "memory")

// ---- prep (R5 verbatim, measured): xb = fp16(x); t partials = x@A^T (K/4). ----
__global__ __launch_bounds__(256) void k_prep(
    const float* __restrict__ x, const float* __restrict__ A,
    unsigned short* __restrict__ xb, float* __restrict__ t) {
    __shared__ float part[64];
    const int s = blockIdx.x >> 2, p = blockIdx.x & 3;
    const int w = threadIdx.x >> 6, lane = threadIdx.x & 63;
    const int kbase = p * 2048 + w * 512;
    const float* xr = x + s * IN_F + kbase;

    f32x4 xv[2];
    #pragma unroll
    for (int j = 0; j < 2; ++j) {
        xv[j] = *(const f32x4*)(xr + j * 256 + lane * 4);
        u16x4 h;
        h[0] = __builtin_bit_cast(unsigned short, (_Float16)xv[j].x);
        h[1] = __builtin_bit_cast(unsigned short, (_Float16)xv[j].y);
        h[2] = __builtin_bit_cast(unsigned short, (_Float16)xv[j].z);
        h[3] = __builtin_bit_cast(unsigned short, (_Float16)xv[j].w);
        *(u16x4*)(xb + s * IN_F + kbase + j * 256 + lane * 4) = h;
    }

    float acc[LORA_R];
    #pragma unroll
    for (int r = 0; r < LORA_R; ++r) acc[r] = 0.f;
    #pragma unroll
    for (int r = 0; r < LORA_R; ++r) {
        const float* ar = A + r * IN_F + kbase;
        #pragma unroll
        for (int j = 0; j < 2; ++j) {
            f32x4 av = *(const f32x4*)(ar + j * 256 + lane * 4);
            acc[r] = fmaf(xv[j].x, av.x, acc[r]);
            acc[r] = fmaf(xv[j].y, av.y, acc[r]);
            acc[r] = fmaf(xv[j].z, av.z, acc[r]);
            acc[r] = fmaf(xv[j].w, av.w, acc[r]);
        }
    }
    #pragma unroll
    for (int r = 0; r < LORA_R; ++r) {
        float v = acc[r];
        #pragma unroll
        for (int off = 32; off; off >>= 1) v += __shfl_down(v, off, 64);
        if (lane == 0) part[w * 16 + r] = v;
    }
    __syncthreads();
    if (threadIdx.x < 16)
        t[s * 64 + p * 16 + threadIdx.x] = part[threadIdx.x] + part[16 + threadIdx.x] +
                                           part[32 + threadIdx.x] + part[48 + threadIdx.x];
}

// ---- main: 256 blocks (32-col n-tile, FULL K), 512 thr = 8 waves, BK=256 ----
// 32 iterations. Chunks: W 16KB (32rows x 128 ints), x 32KB (64rows x 256 f16).
// 3 buffers each, issue-ahead 2 -> ~96KB/CU in flight; uniform vmcnt(6), never
// drained mid-loop (T4). Half the barrier epochs of BK=128. Scales f16 in LDS.
// Per wave/iter: 2 k-slices {wkk, wkk+4} x 4 mt = 8 MFMA.
// XOR swizzle (16B slot ^= row&7) via pre-XOR'd global src; swizzled LDS reads.
// LDS (155904 B): xs 3x32768 | wt 3x16384 @98304 | scs [32][132] f16 @147456
// epilogue alias: accs[8][64*17] f32 @0; tred[64][16] f32 @36864.
__global__ __launch_bounds__(512, 2) void k_main(
    const int* __restrict__ packed, const float* __restrict__ scales,
    const unsigned short* __restrict__ xb, const float* __restrict__ t,
    const float* __restrict__ B, float* __restrict__ out) {
    __shared__ char lds[155904];
    _Float16* xs = (_Float16*)lds;               // 3 x 16384 f16
    int* wt = (int*)(lds + 98304);               // 3 x 4096 int
    _Float16* scs = (_Float16*)(lds + 147456);   // 32*132 f16
    float* accs = (float*)lds;
    float* tred = (float*)(lds + 36864);

    const int tid = threadIdx.x;
    const int n0 = blockIdx.x * 32;
    const int w = tid >> 6, lane = tid & 63;
    const int nh = w >> 2, wkk = w & 3;
    const int q = lane >> 4, c16 = lane & 15;
    const int l5 = lane >> 5, l31 = lane & 31;

    // ---- scales staging: f32 -> f16 once ----
    {
        int row = tid >> 4, g = tid & 15;
        const float* sp = scales + (n0 + row) * (IN_F / 64);
        f32x4 a = *(const f32x4*)(sp + g * 4);
        f32x4 b = *(const f32x4*)(sp + 64 + g * 4);
        u16x4 ha, hb;
        ha[0] = __builtin_bit_cast(unsigned short, (_Float16)a.x);
        ha[1] = __builtin_bit_cast(unsigned short, (_Float16)a.y);
        ha[2] = __builtin_bit_cast(unsigned short, (_Float16)a.z);
        ha[3] = __builtin_bit_cast(unsigned short, (_Float16)a.w);
        hb[0] = __builtin_bit_cast(unsigned short, (_Float16)b.x);
        hb[1] = __builtin_bit_cast(unsigned short, (_Float16)b.y);
        hb[2] = __builtin_bit_cast(unsigned short, (_Float16)b.z);
        hb[3] = __builtin_bit_cast(unsigned short, (_Float16)b.w);
        *(u16x4*)((unsigned short*)scs + row * 132 + g * 4) = ha;
        *(u16x4*)((unsigned short*)scs + row * 132 + 64 + g * 4) = hb;
    }

    // ---- per-lane staging sources, 16B slot pre-XOR'd with (row&7) ----
    // x: 4 gl_lds/wave, rows 8w+2j+l5 (2 rows per gl_lds)
    const unsigned short* xg[4];
    #pragma unroll
    for (int j = 0; j < 4; ++j) {
        int row = 8 * w + 2 * j + l5;
        xg[j] = xb + (size_t)row * IN_F + ((l31 ^ (row & 7)) << 3);
    }
    _Float16* xd = xs + w * 2048;                // + buf*16384 + j*512
    // W: 2 gl_lds/wave, rows 4w+l5 and 4w+2+l5
    const int wr0 = 4 * w + l5, wr1 = wr0 + 2;
    const int* wg0 = packed + (size_t)(n0 + wr0) * (IN_F / 2) + ((l31 ^ (wr0 & 7)) << 2);
    const int* wg1 = packed + (size_t)(n0 + wr1) * (IN_F / 2) + ((l31 ^ (wr1 & 7)) << 2);
    int* wd = wt + w * 512;                      // + buf*4096 (+256 for 2nd)

    // ---- loop-invariant swizzled read offsets ----
    const int row_w = nh * 16 + c16, r7 = c16 & 7;
    const int pvo0 = row_w * 128 + ((4 * wkk + q) ^ r7) * 4;
    const int pvo1 = row_w * 128 + ((4 * (wkk + 4) + q) ^ r7) * 4;
    int afo0[4], afo1[4];
    #pragma unroll
    for (int mt = 0; mt < 4; ++mt) {
        afo0[mt] = (mt * 16 + c16) * 256 + ((4 * wkk + q) ^ r7) * 8;
        afo1[mt] = (mt * 16 + c16) * 256 + ((4 * (wkk + 4) + q) ^ r7) * 8;
    }
    const int scso = row_w * 132 + (wkk >> 1);

    f32x4 acc[4];
    #pragma unroll
    for (int mt = 0; mt < 4; ++mt) acc[mt] = (f32x4){0.f, 0.f, 0.f, 0.f};

    // ---- prologue: stage chunks 0,1 (x first, then W — W(c) is gating op) ----
    #pragma unroll
    for (int c = 0; c < 2; ++c) {
        #pragma unroll
        for (int j = 0; j < 4; ++j)
            gl_lds16(xg[j] + (size_t)c * 256, xd + c * 16384 + j * 512);
        gl_lds16(wg0 + (size_t)c * 128, wd + c * 4096);
        gl_lds16(wg1 + (size_t)c * 128, wd + c * 4096 + 256);
    }
    asm volatile("s_waitcnt lgkmcnt(0)" ::: "memory");   // scs visible
    __builtin_amdgcn_s_barrier();

    const f16x2 c1032 = {(_Float16)1032.0f, (_Float16)1032.0f};

    for (int kt = 0; kt < 32; ++kt) {
        // chunk kt resident (6 newer ops may fly); barrier; issue kt+2
        if (kt < 31) VMCNT(6);
        else         VMCNT(0);
        __builtin_amdgcn_s_barrier();
        __builtin_amdgcn_sched_barrier(0);
        const int cb = kt % 3;
        if (kt <= 29) {
            const int nb = (kt + 2) % 3;
            const size_t xo = (size_t)(kt + 2) * 256;
            const size_t wo = (size_t)(kt + 2) * 128;
            #pragma unroll
            for (int j = 0; j < 4; ++j)
                gl_lds16(xg[j] + xo, xd + nb * 16384 + j * 512);
            gl_lds16(wg0 + wo, wd + nb * 4096);
            gl_lds16(wg1 + wo, wd + nb * 4096 + 256);
        }
        // compute: 2 k-slices from buffer cb
        i32x4 pv0 = *(const i32x4*)(wt + cb * 4096 + pvo0);
        i32x4 pv1 = *(const i32x4*)(wt + cb * 4096 + pvo1);
        _Float16 s0 = scs[scso + kt * 4];
        _Float16 s1 = scs[scso + kt * 4 + 2];
        f16x2 sc0 = {s0, s0}, sc1 = {s1, s1};
        f16x8 bf0, bf1;
        #pragma unroll
        for (int m = 0; m < 4; ++m) {
            unsigned u0 = ((((unsigned)pv0[m] << 12) | (unsigned)pv0[m]) & 0x000F000Fu) | 0x64006400u;
            unsigned u1 = ((((unsigned)pv1[m] << 12) | (unsigned)pv1[m]) & 0x000F000Fu) | 0x64006400u;
            f16x2 h0 = __builtin_bit_cast(f16x2, u0);
            f16x2 h1 = __builtin_bit_cast(f16x2, u1);
            h0 = (h0 - c1032) * sc0;         // exact (q-8)*scale
            h1 = (h1 - c1032) * sc1;
            bf0[2 * m] = h0.x; bf0[2 * m + 1] = h0.y;
            bf1[2 * m] = h1.x; bf1[2 * m + 1] = h1.y;
        }
        const _Float16* xbase = xs + cb * 16384;
        #pragma unroll
        for (int mt = 0; mt < 4; ++mt) {
            f16x8 af = *(const f16x8*)(xbase + afo0[mt]);
            acc[mt] = __builtin_amdgcn_mfma_f32_16x16x32_f16(af, bf0, acc[mt], 0, 0, 0);
        }
        #pragma unroll
        for (int mt = 0; mt < 4; ++mt) {
            f16x8 af = *(const f16x8*)(xbase + afo1[mt]);
            acc[mt] = __builtin_amdgcn_mfma_f32_16x16x32_f16(af, bf1, acc[mt], 0, 0, 0);
        }
    }
    __syncthreads();   // all waves done with xs/wt/scs before alias overwrite

    // ---- epilogue (R5 verbatim shape): partials -> LDS, t reduce, LoRA, store ----
    float* myacc = accs + w * (64 * 17);
    #pragma unroll
    for (int mt = 0; mt < 4; ++mt)
        #pragma unroll
        for (int r = 0; r < 4; ++r)
            myacc[(mt * 16 + q * 4 + r) * 17 + c16] = acc[mt][r];
    #pragma unroll
    for (int jj = 0; jj < 2; ++jj) {
        int p2 = tid + jj * 512;                  // 1024 = 64 s x 16 r
        const float* tp = t + (p2 >> 4) * 64 + (p2 & 15);
        tred[p2] = tp[0] + tp[16] + tp[32] + tp[48];
    }
    __syncthreads();

    #pragma unroll
    for (int j = 0; j < 4; ++j) {
        int p = tid + j * 512;                    // 2048 outputs: s in 0..63, c in 0..31
        int s = p >> 5, c = p & 31;
        const float* ab = accs + (c >> 4) * 4 * (64 * 17) + s * 17 + (c & 15);
        float v = ab[0] + ab[64 * 17] + ab[2 * 64 * 17] + ab[3 * 64 * 17];
        const float* trow = tred + s * 16;
        const float* bp = B + (n0 + c) * LORA_R;
        f32x4 t0 = *(const f32x4*)trow,        t1 = *(const f32x4*)(trow + 4);
        f32x4 t2 = *(const f32x4*)(trow + 8),  t3 = *(const f32x4*)(trow + 12);
        f32x4 b0 = *(const f32x4*)bp,       b1 = *(const f32x4*)(bp + 4);
        f32x4 b2 = *(const f32x4*)(bp + 8), b3 = *(const f32x4*)(bp + 12);
        float lr = t0.x * b0.x + t0.y * b0.y + t0.z * b0.z + t0.w * b0.w
                 + t1.x * b1.x + t1.y * b1.y + t1.z * b1.z + t1.w * b1.w
                 + t2.x * b2.x + t2.y * b2.y + t2.z * b2.z + t2.w * b2.w
                 + t3.x * b3.x + t3.y * b3.y + t3.z * b3.z + t3.w * b3.w;
        v += 2.0f * lr;
        out[s * OUT_F + n0 + c] = v;
    }
}

extern "C" void kernel_launch(void* const* d_in, const int* in_sizes, int n_in,
                              void* d_out, int out_size, void* d_ws, size_t ws_size,
                              hipStream_t stream) {
    const float* x      = (const float*)d_in[0];
    const int* packed   = (const int*)d_in[1];
    const float* scales = (const float*)d_in[2];
    const float* lora_A = (const float*)d_in[3];
    const float* lora_B = (const float*)d_in[4];
    float* out = (float*)d_out;

    unsigned short* xb = (unsigned short*)d_ws;                    // 1 MiB fp16 x
    float* t = (float*)((char*)d_ws + (size_t)SEQ * IN_F * 2);     // 16 KiB partials

    k_prep<<<256, 256, 0, stream>>>(x, lora_A, xb, t);
    k_main<<<256, 512, 0, stream>>>(packed, scales, xb, t, lora_B, out);
}